// Round 3
// baseline (63.810 us; speedup 1.0000x reference)
//
#include <hip/hip_runtime.h>
#include <math.h>

#define CC 5
#define NOUT 1048576   // 8*8*256*64

__device__ __forceinline__ float gelu_exact(float x) {
    return 0.5f * x * (1.0f + erff(x * 0.70710678118654752f));
}

// ---------------------------------------------------------------------------
// Kernel 1: one unit (b,lp) per 512-thread block.
//   Thread (u = tid>>3, j = tid&7): row u of K_unf, contributions from batch
//   j+1 only (~11 elements, compile-time unrolled). Reduce over j via shfl.
//   K stage: ksh[bp][516] (stride 516 -> conflict-free group reads).
// ---------------------------------------------------------------------------
__global__ __launch_bounds__(512) void cluster_main(
    const float* __restrict__ K,
    const float* __restrict__ Wk, const float* __restrict__ bk,
    const float* __restrict__ Wq, const float* __restrict__ bq,
    float* __restrict__ ws_mu, float* __restrict__ ws_lp, float* __restrict__ ws_ctr)
{
    const int blk  = blockIdx.x;
    const int unit = ((blk & 7) << 8) | (blk >> 3);   // spread b across dispatch order
    const int b    = unit >> 8;
    const int lp   = unit & 255;
    const int h    = lp >> 5;
    const int l0   = (lp & 31) << 3;
    const int tid  = threadIdx.x;

    __shared__ float4 WW4[512 * 3];   // row m: [wk0..3][wk4,wq0..2][wq3,wq4,-,-]
    __shared__ float  ksh[7 * 516];   // [bp][sd] stride 516
    __shared__ float  rows[50 * 8];   // per-u: qv[5], ind, logp

    {
        const float* wkp = Wk + tid * 5;
        const float* wqp = Wq + tid * 5;
        WW4[tid * 3 + 0] = make_float4(wkp[0], wkp[1], wkp[2], wkp[3]);
        WW4[tid * 3 + 1] = make_float4(wkp[4], wqp[0], wqp[1], wqp[2]);
        WW4[tid * 3 + 2] = make_float4(wqp[3], wqp[4], 0.f, 0.f);
    }
    const int nk = b << 9;
    for (int i = tid; i < nk; i += 512) {
        int bp = i >> 9, sd = i & 511;
        ksh[bp * 516 + sd] =
            K[((((bp + 1) * 8 + h) * 256) + (l0 + (sd >> 6))) * 64 + (sd & 63)];
    }
    __syncthreads();

    const int u = tid >> 3;
    const int j = tid & 7;

    float ak[CC] = {0.f, 0.f, 0.f, 0.f, 0.f};
    float aq[CC] = {0.f, 0.f, 0.f, 0.f, 0.f};
    if (u < 50 && j < b) {
        const int usrc = 50 - b + j;       // residue class mod 50
        const int q0 = u << 9;
        const int r0 = q0 % 50;
        int delta = usrc - r0; if (delta < 0) delta += 50;
        int m = delta;                      // column in [0,512), step 50
        int B = (q0 + delta) / 50;          // s*64+d, step 1
        const float* kp = ksh + j * 516;
        #pragma unroll
        for (int it = 0; it < 11; ++it) {
            if (m < 512) {
                float x = kp[B];
                int mm = m * 3;
                float4 w0 = WW4[mm], w1 = WW4[mm + 1], w2 = WW4[mm + 2];
                ak[0] = fmaf(x, w0.x, ak[0]);
                ak[1] = fmaf(x, w0.y, ak[1]);
                ak[2] = fmaf(x, w0.z, ak[2]);
                ak[3] = fmaf(x, w0.w, ak[3]);
                ak[4] = fmaf(x, w1.x, ak[4]);
                aq[0] = fmaf(x, w1.y, aq[0]);
                aq[1] = fmaf(x, w1.z, aq[1]);
                aq[2] = fmaf(x, w1.w, aq[2]);
                aq[3] = fmaf(x, w2.x, aq[3]);
                aq[4] = fmaf(x, w2.y, aq[4]);
            }
            m += 50; ++B;
        }
    }
    // reduce over j within 8-lane groups
    #pragma unroll
    for (int off = 4; off; off >>= 1) {
        #pragma unroll
        for (int c = 0; c < CC; ++c) {
            ak[c] += __shfl_down(ak[c], off, 8);
            aq[c] += __shfl_down(aq[c], off, 8);
        }
    }

    if (u < 50 && j == 0) {
        float gk[CC], gq[CC];
        float mk = -1e30f, mq = -1e30f;
        #pragma unroll
        for (int c = 0; c < CC; ++c) {
            gk[c] = gelu_exact(ak[c] + bk[c]); mk = fmaxf(mk, gk[c]);
            gq[c] = gelu_exact(aq[c] + bq[c]); mq = fmaxf(mq, gq[c]);
        }
        float sk = 0.f, sq = 0.f;
        #pragma unroll
        for (int c = 0; c < CC; ++c) {
            gk[c] = expf(gk[c] - mk); sk += gk[c];
            gq[c] = expf(gq[c] - mq); sq += gq[c];
        }
        float rsk = 1.f / sk, rsq = 1.f / sq;
        float qv[CC];
        float sumq = 0.f, sumk = 0.f;
        #pragma unroll
        for (int c = 0; c < CC; ++c) {
            float kvc = gk[c] * rsk; sumk += kvc;
            qv[c] = gq[c] * rsq;     sumq += qv[c];
        }
        float mu = sumq * 0.2f;
        float xb = sumk * 0.2f;
        float var = 0.f;
        #pragma unroll
        for (int c = 0; c < CC; ++c) { float dq = qv[c] - mu; var = fmaf(dq, dq, var); }
        var *= 0.25f;                         // ddof=1
        float sd_ = sqrtf(var);
        float sigma = log1pf(expf(sd_));      // softplus
        float z = (xb - mu) / sigma;
        float logp = -0.5f * z * z - logf(sigma) - 0.91893853320467274f;
        int ind = 0; float bv = qv[0];
        #pragma unroll
        for (int c = 1; c < CC; ++c) if (qv[c] > bv) { bv = qv[c]; ind = c; }

        ws_mu[(b * 50 + u) * 256 + lp] = mu;
        float* row = rows + u * 8;
        #pragma unroll
        for (int c = 0; c < CC; ++c) row[c] = qv[c];
        row[5] = (float)ind;
        row[6] = logp;
    }
    __syncthreads();

    if (tid < 26) {
        const float fi = (float)(tid / 5);
        const int sel = (tid < 25) ? (tid % 5) : 6;
        const bool always = (tid == 25);
        float acc = 0.f;
        for (int u2 = 0; u2 < 50; ++u2) {
            float v = rows[u2 * 8 + sel];
            float f = rows[u2 * 8 + 5];
            acc += (always || f != fi) ? v : 0.f;
        }
        if (tid < 25) ws_ctr[unit * 25 + tid] = acc * 0.02f;   // mean over 50
        else          ws_lp[unit] = acc;
    }
}

// ---------------------------------------------------------------------------
// Kernel 2 (merged): blocks 0..1023 = backmap (1024 outputs each);
//                    block 1024    = loss finalize.
//   backmap: out[o] = max_c2 gelu(z_c2) = max(gelu(min z), gelu(max z))
//   (exact GELU is unimodal with a single minimum -> extremes suffice).
// ---------------------------------------------------------------------------
__global__ __launch_bounds__(1024) void backfin(
    const float* __restrict__ Wb, const float* __restrict__ bb,
    const float* __restrict__ ws_ctr, const float* __restrict__ ws_mu,
    const float* __restrict__ ws_lp, float* __restrict__ out)
{
    const int tid = threadIdx.x;

    if (blockIdx.x < 1024) {
        __shared__ float ct[10][5];        // [c2*2+half][k]
        const int o0 = blockIdx.x << 10;
        const int b2 = o0 >> 17;
        const int h2 = (o0 >> 14) & 7;
        const int r0 = o0 & 16383;
        if (tid < 50) {
            int c2 = tid / 10, hf = (tid / 5) & 1, k = tid % 5;
            int p = b2 * 655360 + h2 * 81920 + r0 + c2 * 16384 + hf * 512;
            int c = p >> 20;
            int un = (p >> 9) & 2047;
            ct[c2 * 2 + hf][k] = ws_ctr[un * 25 + c * 5 + k];
        }
        __syncthreads();

        const int m  = tid & 511;
        const int hf = tid >> 9;
        const float w0 = Wb[m], w1 = Wb[512 + m], w2 = Wb[1024 + m],
                    w3 = Wb[1536 + m], w4 = Wb[2048 + m];
        const float bias = bb[m];
        float zmin = INFINITY, zmax = -INFINITY;
        #pragma unroll
        for (int c2 = 0; c2 < 5; ++c2) {
            const float* c5 = ct[c2 * 2 + hf];
            float z = bias;
            z = fmaf(c5[0], w0, z);
            z = fmaf(c5[1], w1, z);
            z = fmaf(c5[2], w2, z);
            z = fmaf(c5[3], w3, z);
            z = fmaf(c5[4], w4, z);
            zmin = fminf(zmin, z);
            zmax = fmaxf(zmax, z);
        }
        out[o0 + tid] = fmaxf(gelu_exact(zmin), gelu_exact(zmax));
        return;
    }

    // ---- finalize block ----
    const int wave = tid >> 6;
    const int lane = tid & 63;
    __shared__ float red[1024];
    __shared__ float total_lp_sh;
    __shared__ float cew[16];

    red[tid] = ws_lp[tid] + ws_lp[tid + 1024];
    __syncthreads();
    for (int s = 512; s > 0; s >>= 1) {
        if (tid < s) red[tid] += red[tid + s];
        __syncthreads();
    }
    if (tid == 0) total_lp_sh = red[0];

    float ce_part = 0.0f;
    for (int pair = wave; pair < 400; pair += 16) {
        const float* mp = ws_mu + pair * 256;
        float v0 = mp[lane], v1 = mp[lane + 64], v2 = mp[lane + 128], v3 = mp[lane + 192];
        float mx = fmaxf(fmaxf(v0, v1), fmaxf(v2, v3));
        #pragma unroll
        for (int off = 1; off < 64; off <<= 1) mx = fmaxf(mx, __shfl_xor(mx, off, 64));
        float se = expf(v0 - mx) + expf(v1 - mx) + expf(v2 - mx) + expf(v3 - mx);
        #pragma unroll
        for (int off = 1; off < 64; off <<= 1) se += __shfl_xor(se, off, 64);
        float lse = mx + logf(se);
        float a = -(v0 * (v0 - lse) + v1 * (v1 - lse) + v2 * (v2 - lse) + v3 * (v3 - lse));
        #pragma unroll
        for (int off = 1; off < 64; off <<= 1) a += __shfl_xor(a, off, 64);
        ce_part += a;
    }
    if (lane == 0) cew[wave] = ce_part;
    __syncthreads();
    if (tid == 0) {
        float ce = 0.0f;
        #pragma unroll
        for (int w = 0; w < 16; ++w) ce += cew[w];
        ce *= (1.0f / 400.0f);
        float loss = -(total_lp_sh * (1.0f / 102400.0f)) + ce;
        out[NOUT] = loss;
    }
}

extern "C" void kernel_launch(void* const* d_in, const int* in_sizes, int n_in,
                              void* d_out, int out_size, void* d_ws, size_t ws_size,
                              hipStream_t stream) {
    const float* K  = (const float*)d_in[0];
    // d_in[1] = V, unused by the reference
    const float* Wk = (const float*)d_in[2];
    const float* bk = (const float*)d_in[3];
    const float* Wq = (const float*)d_in[4];
    const float* bq = (const float*)d_in[5];
    const float* Wb = (const float*)d_in[6];
    const float* bb = (const float*)d_in[7];
    float* out    = (float*)d_out;
    float* ws_mu  = (float*)d_ws;            // 102400 floats  [b][u][lp]
    float* ws_lp  = ws_mu + 102400;          // 2048 floats    per-unit logp sums
    float* ws_ctr = ws_lp + 2048;            // 2048*25 floats per-unit centers

    cluster_main<<<2048, 512, 0, stream>>>(K, Wk, bk, Wq, bq, ws_mu, ws_lp, ws_ctr);
    backfin<<<1025, 1024, 0, stream>>>(Wb, bb, ws_ctr, ws_mu, ws_lp, out);
}